// Round 4
// baseline (1805.548 us; speedup 1.0000x reference)
//
#include <hip/hip_runtime.h>
#include <hip/hip_bf16.h>
#include <math.h>

#define T_SEQ 512
#define BATCH 64
#define DIN   128
#define H     160
#define G3    480   // 3*H

__device__ __forceinline__ float sigmoidf_(float x) {
    return 1.0f / (1.0f + __expf(-x));
}
__device__ __forceinline__ float tanhf_(float x) {
    float a = fabsf(x);
    float e = __expf(2.0f * a);
    float t = 1.0f - 2.0f / (e + 1.0f);
    return copysignf(t, x);
}

// ---------------- block reductions (512 threads = 8 waves) ----------------
__device__ __forceinline__ float blockReduceSum(float v, float* red) {
    #pragma unroll
    for (int off = 32; off > 0; off >>= 1) v += __shfl_down(v, off, 64);
    int wave = threadIdx.x >> 6, lane = threadIdx.x & 63;
    __syncthreads();                 // protect red from previous use
    if (lane == 0) red[wave] = v;
    __syncthreads();
    float s = red[0];
    int nw = blockDim.x >> 6;
    for (int i = 1; i < nw; ++i) s += red[i];
    return s;
}
__device__ __forceinline__ float blockReduceMax(float v, float* red) {
    #pragma unroll
    for (int off = 32; off > 0; off >>= 1) v = fmaxf(v, __shfl_down(v, off, 64));
    int wave = threadIdx.x >> 6, lane = threadIdx.x & 63;
    __syncthreads();
    if (lane == 0) red[wave] = v;
    __syncthreads();
    float s = red[0];
    int nw = blockDim.x >> 6;
    for (int i = 1; i < nw; ++i) s = fmaxf(s, red[i]);
    return s;
}

// ---------------- tiled fp32 GEMM: C[M,N] = A[M,K] * B[N,K]^T + bias, opt tanh ----
__global__ __launch_bounds__(256) void gemm_bias_kernel(
    const float* __restrict__ A, const float* __restrict__ B,
    const float* __restrict__ bias, float* __restrict__ C,
    int M, int N, int K, int act)
{
    const int BM = 64, BN = 64, BK = 32;
    __shared__ __align__(16) float As[BK][BM];   // k-major
    __shared__ __align__(16) float Bs[BK][BN];
    int tid  = threadIdx.x;
    int row0 = blockIdx.x * BM;
    int col0 = blockIdx.y * BN;
    int tx = tid & 15, ty = tid >> 4;
    float acc[4][4] = {};

    for (int k0 = 0; k0 < K; k0 += BK) {
        #pragma unroll
        for (int v = 0; v < 2; ++v) {
            int idx = tid + v * 256;       // 0..511 over 64 rows x 8 vec4
            int m   = idx >> 3;
            int kq  = (idx & 7) << 2;
            float4 a4 = *reinterpret_cast<const float4*>(A + (size_t)(row0 + m) * K + k0 + kq);
            As[kq + 0][m] = a4.x; As[kq + 1][m] = a4.y;
            As[kq + 2][m] = a4.z; As[kq + 3][m] = a4.w;
            float4 b4 = make_float4(0.f, 0.f, 0.f, 0.f);
            if (col0 + m < N)
                b4 = *reinterpret_cast<const float4*>(B + (size_t)(col0 + m) * K + k0 + kq);
            Bs[kq + 0][m] = b4.x; Bs[kq + 1][m] = b4.y;
            Bs[kq + 2][m] = b4.z; Bs[kq + 3][m] = b4.w;
        }
        __syncthreads();
        #pragma unroll
        for (int kk = 0; kk < BK; ++kk) {
            float4 a4 = *reinterpret_cast<const float4*>(&As[kk][ty << 2]);
            float4 b4 = *reinterpret_cast<const float4*>(&Bs[kk][tx << 2]);
            float av[4] = {a4.x, a4.y, a4.z, a4.w};
            float bv[4] = {b4.x, b4.y, b4.z, b4.w};
            #pragma unroll
            for (int i = 0; i < 4; ++i)
                #pragma unroll
                for (int j = 0; j < 4; ++j) acc[i][j] += av[i] * bv[j];
        }
        __syncthreads();
    }
    #pragma unroll
    for (int i = 0; i < 4; ++i) {
        int row = row0 + (ty << 2) + i;
        #pragma unroll
        for (int j = 0; j < 4; ++j) {
            int col = col0 + (tx << 2) + j;
            if (col < N) {
                float v = acc[i][j] + bias[col];
                if (act == 1) v = tanhf_(v);
                C[(size_t)row * N + col] = v;
            }
        }
    }
}

// ---------------- GRU recurrence: one block per (batch, dir) ----------------
// 1024 threads = 16 waves = 4 waves/SIMD -> VGPR budget 128.
// __launch_bounds__(1024, 4) declares exactly that so the allocator does NOT
// target 8 waves/SIMD (<=64 VGPR), which spilled the weights in rounds 1-2
// (VGPR_Count=60 with an 80-float array => scratch traffic, VALUBusy 36%).
// Thread = (row r = tid>>1, K-half = tid&1); 20 NAMED float4 registers hold
// the 80 weights (named scalars can't be heuristically spilled like arrays).
// Partner lanes (tid^1, same wave) combine via __shfl_xor.
// xw: [B][T][960] (dir0: 0..479, dir1: 480..959), whh: [2][480][160],
// bhh: [2][480], out: [B][T][320] (dir0 -> 0..159, dir1 -> 160..319)
#define DOT4(hv, wv) ((hv).x*(wv).x + (hv).y*(wv).y + (hv).z*(wv).z + (hv).w*(wv).w)

__global__ __launch_bounds__(1024, 4) void gru_kernel(
    const float* __restrict__ xw, const float* __restrict__ whh,
    const float* __restrict__ bhh, float* __restrict__ out)
{
    int b    = blockIdx.x >> 1;
    int dir  = blockIdx.x & 1;
    int tid  = threadIdx.x;
    int r    = tid >> 1;
    int half = tid & 1;
    bool active = (tid < 2 * G3);
    __shared__ __align__(16) float h_s[H];
    __shared__ float g_s[G3];

    float4 w0  = {}, w1  = {}, w2  = {}, w3  = {}, w4  = {};
    float4 w5  = {}, w6  = {}, w7  = {}, w8  = {}, w9  = {};
    float4 w10 = {}, w11 = {}, w12 = {}, w13 = {}, w14 = {};
    float4 w15 = {}, w16 = {}, w17 = {}, w18 = {}, w19 = {};
    float bias = 0.f;
    if (active) {
        const float4* wp4 = reinterpret_cast<const float4*>(
            whh + (size_t)dir * G3 * H + (size_t)r * H + half * 80);
        w0  = wp4[0];  w1  = wp4[1];  w2  = wp4[2];  w3  = wp4[3];  w4  = wp4[4];
        w5  = wp4[5];  w6  = wp4[6];  w7  = wp4[7];  w8  = wp4[8];  w9  = wp4[9];
        w10 = wp4[10]; w11 = wp4[11]; w12 = wp4[12]; w13 = wp4[13]; w14 = wp4[14];
        w15 = wp4[15]; w16 = wp4[16]; w17 = wp4[17]; w18 = wp4[18]; w19 = wp4[19];
        bias = bhh[dir * G3 + r];
    }
    if (tid < H) h_s[tid] = 0.f;
    __syncthreads();

    // preload xw for step 0
    float xr = 0.f, xz = 0.f, xn = 0.f;
    {
        int tt0 = dir ? (T_SEQ - 1) : 0;
        size_t base0 = ((size_t)b * T_SEQ + tt0) * 960 + (size_t)dir * G3;
        if (tid < H) {
            xr = xw[base0 + tid];
            xz = xw[base0 + H + tid];
            xn = xw[base0 + 2 * H + tid];
        }
    }

    for (int step = 0; step < T_SEQ; ++step) {
        int tt = dir ? (T_SEQ - 1 - step) : step;
        // prefetch step+1's xW: latency hides under this step's dot + barrier
        float nxr = 0.f, nxz = 0.f, nxn = 0.f;
        {
            int sn  = (step + 1 < T_SEQ) ? step + 1 : step;
            int ttn = dir ? (T_SEQ - 1 - sn) : sn;
            size_t basen = ((size_t)b * T_SEQ + ttn) * 960 + (size_t)dir * G3;
            if (tid < H) {
                nxr = xw[basen + tid];
                nxz = xw[basen + H + tid];
                nxn = xw[basen + 2 * H + tid];
            }
        }
        // 80-MAC dot, 4 ILP accumulators; LDS reads are 2-address broadcast
        float acc0 = 0.f, acc1 = 0.f, acc2 = 0.f, acc3 = 0.f;
        {
            const float4* hp4 = reinterpret_cast<const float4*>(h_s) + half * 20;
            acc0 += DOT4(hp4[0],  w0);   acc1 += DOT4(hp4[1],  w1);
            acc2 += DOT4(hp4[2],  w2);   acc3 += DOT4(hp4[3],  w3);
            acc0 += DOT4(hp4[4],  w4);   acc1 += DOT4(hp4[5],  w5);
            acc2 += DOT4(hp4[6],  w6);   acc3 += DOT4(hp4[7],  w7);
            acc0 += DOT4(hp4[8],  w8);   acc1 += DOT4(hp4[9],  w9);
            acc2 += DOT4(hp4[10], w10);  acc3 += DOT4(hp4[11], w11);
            acc0 += DOT4(hp4[12], w12);  acc1 += DOT4(hp4[13], w13);
            acc2 += DOT4(hp4[14], w14);  acc3 += DOT4(hp4[15], w15);
            acc0 += DOT4(hp4[16], w16);  acc1 += DOT4(hp4[17], w17);
            acc2 += DOT4(hp4[18], w18);  acc3 += DOT4(hp4[19], w19);
        }
        float s = (acc0 + acc1) + (acc2 + acc3);
        s += __shfl_xor(s, 1);           // partner lane tid^1: full 160-dot
        if (active && half == 0) g_s[r] = s + bias;
        __syncthreads();
        if (tid < H) {
            float rg = sigmoidf_(xr + g_s[tid]);
            float z  = sigmoidf_(xz + g_s[H + tid]);
            float n  = tanhf_(xn + rg * g_s[2 * H + tid]);
            float hn = (1.0f - z) * n + z * h_s[tid];
            h_s[tid] = hn;
            out[((size_t)b * T_SEQ + tt) * 320 + (size_t)dir * H + tid] = hn;
        }
        __syncthreads();
        xr = nxr; xz = nxz; xn = nxn;
    }
}

// ---------------- attn logits: [32768][4] = keys[tok][160] . score_w[h][160] + b ---
__global__ __launch_bounds__(256) void logits_kernel(
    const float* __restrict__ keys, const float* __restrict__ sw,
    const float* __restrict__ sb, float* __restrict__ out)
{
    int gid = blockIdx.x * 256 + threadIdx.x;
    int tok = gid >> 2, h = gid & 3;
    const float4* kr = reinterpret_cast<const float4*>(keys + (size_t)tok * H);
    const float4* wr = reinterpret_cast<const float4*>(sw + (size_t)h * H);
    float acc = 0.f;
    #pragma unroll
    for (int i = 0; i < H / 4; ++i) {
        float4 a = kr[i], w4 = wr[i];
        acc += a.x * w4.x + a.y * w4.y + a.z * w4.z + a.w * w4.w;
    }
    out[gid] = acc + sb[h];
}

// ---------------- epilogue: motion + softmax + pool + proj + LN + L2, 1 block/batch --
__global__ __launch_bounds__(512) void final_kernel(
    const float* __restrict__ x, const float* __restrict__ logits,
    const float* __restrict__ seq, const float* __restrict__ proj_w,
    const float* __restrict__ proj_b, const float* __restrict__ ln_g,
    const float* __restrict__ ln_b, float* __restrict__ out)
{
    int b   = blockIdx.x;
    int tid = threadIdx.x;
    __shared__ float ms[T_SEQ];
    __shared__ float ss[T_SEQ];
    __shared__ __align__(16) float pooled[320];
    __shared__ float red[8];

    // Phase A: motion[t] = ||x[t]-x[t-1]||, m[0]=m[1]; standardize (ddof=1)
    {
        float m = 0.f;
        if (tid >= 1) {
            const float4* xc = reinterpret_cast<const float4*>(x + ((size_t)b * T_SEQ + tid) * DIN);
            const float4* xp = reinterpret_cast<const float4*>(x + ((size_t)b * T_SEQ + tid - 1) * DIN);
            float s = 0.f;
            #pragma unroll
            for (int i = 0; i < DIN / 4; ++i) {
                float4 a = xc[i], p = xp[i];
                float dx = a.x - p.x, dy = a.y - p.y, dz = a.z - p.z, dw = a.w - p.w;
                s += dx * dx + dy * dy + dz * dz + dw * dw;
            }
            m = sqrtf(s);
        }
        ms[tid] = m;
    }
    __syncthreads();
    if (tid == 0) ms[0] = ms[1];
    __syncthreads();
    float mv   = ms[tid];
    float mean = blockReduceSum(mv, red) * (1.0f / T_SEQ);
    float var  = blockReduceSum((mv - mean) * (mv - mean), red) * (1.0f / (T_SEQ - 1));
    float mstd = (mv - mean) / (sqrtf(var) + 1e-6f);

    // Phase B: 4 softmaxes over t; s[t] = mean_h weights
    float4 lg = *reinterpret_cast<const float4*>(logits + ((size_t)b * T_SEQ + tid) * 4);
    float l[4] = {lg.x + mstd, lg.y + mstd, lg.z + mstd, lg.w + mstd};
    float ssum = 0.f;
    #pragma unroll
    for (int h = 0; h < 4; ++h) {
        float mx = blockReduceMax(l[h], red);
        float e  = __expf(l[h] - mx);
        float se = blockReduceSum(e, red);
        float wv = e / se;
        ssum += wv;
    }
    float sv = ssum * 0.25f;
    ss[tid] = sv;
    out[16384 + b * T_SEQ + tid] = sv;   // output 1: weights.mean(axis=2)
    __syncthreads();

    // Phase C: pooled[d] = sum_t seq[b,t,d] * s[t]
    if (tid < 320) {
        float acc = 0.f;
        const float* sp = seq + (size_t)b * T_SEQ * 320 + tid;
        #pragma unroll 4
        for (int t = 0; t < T_SEQ; ++t) acc += sp[(size_t)t * 320] * ss[t];
        pooled[tid] = acc;
    }
    __syncthreads();

    // Phase D: embedding = pooled . proj_w^T + b ; LN ; L2-normalize
    float e = 0.f;
    if (tid < 256) {
        const float4* pw = reinterpret_cast<const float4*>(proj_w + (size_t)tid * 320);
        const float4* pl = reinterpret_cast<const float4*>(pooled);
        float acc = 0.f;
        #pragma unroll
        for (int i = 0; i < 80; ++i) {
            float4 w4 = pw[i], p4 = pl[i];
            acc += w4.x * p4.x + w4.y * p4.y + w4.z * p4.z + w4.w * p4.w;
        }
        e = acc + proj_b[tid];
    }
    float mu = blockReduceSum(tid < 256 ? e : 0.f, red) * (1.0f / 256);
    float dv = (tid < 256) ? (e - mu) : 0.f;
    float vr = blockReduceSum(dv * dv, red) * (1.0f / 256);
    float g  = 0.f;
    if (tid < 256) g = (e - mu) * rsqrtf(vr + 1e-5f) * ln_g[tid] + ln_b[tid];
    float nrm = sqrtf(blockReduceSum(g * g, red));
    nrm = fmaxf(nrm, 1e-12f);
    if (tid < 256) out[b * 256 + tid] = g / nrm;
}

extern "C" void kernel_launch(void* const* d_in, const int* in_sizes, int n_in,
                              void* d_out, int out_size, void* d_ws, size_t ws_size,
                              hipStream_t stream) {
    const float* x       = (const float*)d_in[0];
    const float* Wih0    = (const float*)d_in[1];
    const float* Whh0    = (const float*)d_in[2];
    const float* bih0    = (const float*)d_in[3];
    const float* bhh0    = (const float*)d_in[4];
    const float* Wih1    = (const float*)d_in[5];
    const float* Whh1    = (const float*)d_in[6];
    const float* bih1    = (const float*)d_in[7];
    const float* bhh1    = (const float*)d_in[8];
    const float* key_w   = (const float*)d_in[9];
    const float* key_b   = (const float*)d_in[10];
    const float* score_w = (const float*)d_in[11];
    const float* score_b = (const float*)d_in[12];
    const float* proj_w  = (const float*)d_in[13];
    const float* proj_b  = (const float*)d_in[14];
    const float* ln_g    = (const float*)d_in[15];
    const float* ln_b    = (const float*)d_in[16];

    float* ws    = (float*)d_ws;
    float* xwbuf = ws;                        // 32768*960  = 31457280 (reused for xw1)
    float* h1    = ws + 31457280;             // 32768*320  = 10485760
    float* seq   = h1 + 10485760;             // 32768*320  = 10485760
    float* keys  = seq + 10485760;            // 32768*160  =  5242880
    float* lgts  = keys + 5242880;            // 32768*4    =   131072
    float* outf  = (float*)d_out;

    const int M = BATCH * T_SEQ;              // 32768

    gemm_bias_kernel<<<dim3(M / 64, 15), 256, 0, stream>>>(x,   Wih0, bih0, xwbuf, M, 960, 128, 0);
    gru_kernel<<<128, 1024, 0, stream>>>(xwbuf, Whh0, bhh0, h1);
    gemm_bias_kernel<<<dim3(M / 64, 15), 256, 0, stream>>>(h1,  Wih1, bih1, xwbuf, M, 960, 320, 0);
    gru_kernel<<<128, 1024, 0, stream>>>(xwbuf, Whh1, bhh1, seq);
    gemm_bias_kernel<<<dim3(M / 64, 3),  256, 0, stream>>>(seq, key_w, key_b, keys, M, 160, 320, 1);
    logits_kernel<<<512, 256, 0, stream>>>(keys, score_w, score_b, lgts);
    final_kernel<<<64, 512, 0, stream>>>(x, lgts, seq, proj_w, proj_b, ln_g, ln_b, outf);
}

// Round 5
// 1801.988 us; speedup vs baseline: 1.0020x; 1.0020x over previous
//
#include <hip/hip_runtime.h>
#include <hip/hip_bf16.h>
#include <math.h>

#define T_SEQ 512
#define BATCH 64
#define DIN   128
#define H     160
#define G3    480   // 3*H

__device__ __forceinline__ float sigmoidf_(float x) {
    return 1.0f / (1.0f + __expf(-x));
}
__device__ __forceinline__ float tanhf_(float x) {
    float a = fabsf(x);
    float e = __expf(2.0f * a);
    float t = 1.0f - 2.0f / (e + 1.0f);
    return copysignf(t, x);
}

// ---------------- block reductions (512 threads = 8 waves) ----------------
__device__ __forceinline__ float blockReduceSum(float v, float* red) {
    #pragma unroll
    for (int off = 32; off > 0; off >>= 1) v += __shfl_down(v, off, 64);
    int wave = threadIdx.x >> 6, lane = threadIdx.x & 63;
    __syncthreads();                 // protect red from previous use
    if (lane == 0) red[wave] = v;
    __syncthreads();
    float s = red[0];
    int nw = blockDim.x >> 6;
    for (int i = 1; i < nw; ++i) s += red[i];
    return s;
}
__device__ __forceinline__ float blockReduceMax(float v, float* red) {
    #pragma unroll
    for (int off = 32; off > 0; off >>= 1) v = fmaxf(v, __shfl_down(v, off, 64));
    int wave = threadIdx.x >> 6, lane = threadIdx.x & 63;
    __syncthreads();
    if (lane == 0) red[wave] = v;
    __syncthreads();
    float s = red[0];
    int nw = blockDim.x >> 6;
    for (int i = 1; i < nw; ++i) s = fmaxf(s, red[i]);
    return s;
}

// ---------------- tiled fp32 GEMM: C[M,N] = A[M,K] * B[N,K]^T + bias, opt tanh ----
__global__ __launch_bounds__(256) void gemm_bias_kernel(
    const float* __restrict__ A, const float* __restrict__ B,
    const float* __restrict__ bias, float* __restrict__ C,
    int M, int N, int K, int act)
{
    const int BM = 64, BN = 64, BK = 32;
    __shared__ __align__(16) float As[BK][BM];   // k-major
    __shared__ __align__(16) float Bs[BK][BN];
    int tid  = threadIdx.x;
    int row0 = blockIdx.x * BM;
    int col0 = blockIdx.y * BN;
    int tx = tid & 15, ty = tid >> 4;
    float acc[4][4] = {};

    for (int k0 = 0; k0 < K; k0 += BK) {
        #pragma unroll
        for (int v = 0; v < 2; ++v) {
            int idx = tid + v * 256;       // 0..511 over 64 rows x 8 vec4
            int m   = idx >> 3;
            int kq  = (idx & 7) << 2;
            float4 a4 = *reinterpret_cast<const float4*>(A + (size_t)(row0 + m) * K + k0 + kq);
            As[kq + 0][m] = a4.x; As[kq + 1][m] = a4.y;
            As[kq + 2][m] = a4.z; As[kq + 3][m] = a4.w;
            float4 b4 = make_float4(0.f, 0.f, 0.f, 0.f);
            if (col0 + m < N)
                b4 = *reinterpret_cast<const float4*>(B + (size_t)(col0 + m) * K + k0 + kq);
            Bs[kq + 0][m] = b4.x; Bs[kq + 1][m] = b4.y;
            Bs[kq + 2][m] = b4.z; Bs[kq + 3][m] = b4.w;
        }
        __syncthreads();
        #pragma unroll
        for (int kk = 0; kk < BK; ++kk) {
            float4 a4 = *reinterpret_cast<const float4*>(&As[kk][ty << 2]);
            float4 b4 = *reinterpret_cast<const float4*>(&Bs[kk][tx << 2]);
            float av[4] = {a4.x, a4.y, a4.z, a4.w};
            float bv[4] = {b4.x, b4.y, b4.z, b4.w};
            #pragma unroll
            for (int i = 0; i < 4; ++i)
                #pragma unroll
                for (int j = 0; j < 4; ++j) acc[i][j] += av[i] * bv[j];
        }
        __syncthreads();
    }
    #pragma unroll
    for (int i = 0; i < 4; ++i) {
        int row = row0 + (ty << 2) + i;
        #pragma unroll
        for (int j = 0; j < 4; ++j) {
            int col = col0 + (tx << 2) + j;
            if (col < N) {
                float v = acc[i][j] + bias[col];
                if (act == 1) v = tanhf_(v);
                C[(size_t)row * N + col] = v;
            }
        }
    }
}

// ---------------- GRU recurrence: one block per (batch, dir) ----------------
// 1024 threads = 16 waves = 4 waves/SIMD.
// amdgpu_waves_per_eu(4,4): min=MAX=4 waves/EU. Round-4 evidence: with only a
// minimum declared (launch_bounds 2nd arg), the allocator still targeted
// 8 waves/EU (2 blocks/CU fit in LDS), capped itself at 64 VGPR (observed
// VGPR_Count=60) and spilled all 80 weight floats -> 307 KB/CU/step scratch
// reloads, VALUBusy 35%, 615 us. max=4 grants the full 128-VGPR budget so the
// 20 named float4 weight registers stay resident.
// Thread = (row r = tid>>1, K-half = tid&1); partner lanes (tid^1, same wave)
// combine via __shfl_xor.
// xw: [B][T][960] (dir0: 0..479, dir1: 480..959), whh: [2][480][160],
// bhh: [2][480], out: [B][T][320] (dir0 -> 0..159, dir1 -> 160..319)
#define DOT4(hv, wv) ((hv).x*(wv).x + (hv).y*(wv).y + (hv).z*(wv).z + (hv).w*(wv).w)

__global__ __launch_bounds__(1024)
__attribute__((amdgpu_waves_per_eu(4, 4)))
void gru_kernel(
    const float* __restrict__ xw, const float* __restrict__ whh,
    const float* __restrict__ bhh, float* __restrict__ out)
{
    int b    = blockIdx.x >> 1;
    int dir  = blockIdx.x & 1;
    int tid  = threadIdx.x;
    int r    = tid >> 1;
    int half = tid & 1;
    bool active = (tid < 2 * G3);
    __shared__ __align__(16) float h_s[H];
    __shared__ float g_s[G3];

    float4 w0  = {}, w1  = {}, w2  = {}, w3  = {}, w4  = {};
    float4 w5  = {}, w6  = {}, w7  = {}, w8  = {}, w9  = {};
    float4 w10 = {}, w11 = {}, w12 = {}, w13 = {}, w14 = {};
    float4 w15 = {}, w16 = {}, w17 = {}, w18 = {}, w19 = {};
    float bias = 0.f;
    if (active) {
        const float4* wp4 = reinterpret_cast<const float4*>(
            whh + (size_t)dir * G3 * H + (size_t)r * H + half * 80);
        w0  = wp4[0];  w1  = wp4[1];  w2  = wp4[2];  w3  = wp4[3];  w4  = wp4[4];
        w5  = wp4[5];  w6  = wp4[6];  w7  = wp4[7];  w8  = wp4[8];  w9  = wp4[9];
        w10 = wp4[10]; w11 = wp4[11]; w12 = wp4[12]; w13 = wp4[13]; w14 = wp4[14];
        w15 = wp4[15]; w16 = wp4[16]; w17 = wp4[17]; w18 = wp4[18]; w19 = wp4[19];
        bias = bhh[dir * G3 + r];
    }
    if (tid < H) h_s[tid] = 0.f;
    __syncthreads();

    // preload xw for step 0
    float xr = 0.f, xz = 0.f, xn = 0.f;
    {
        int tt0 = dir ? (T_SEQ - 1) : 0;
        size_t base0 = ((size_t)b * T_SEQ + tt0) * 960 + (size_t)dir * G3;
        if (tid < H) {
            xr = xw[base0 + tid];
            xz = xw[base0 + H + tid];
            xn = xw[base0 + 2 * H + tid];
        }
    }

    for (int step = 0; step < T_SEQ; ++step) {
        int tt = dir ? (T_SEQ - 1 - step) : step;
        // prefetch step+1's xW: latency hides under this step's dot + barrier
        float nxr = 0.f, nxz = 0.f, nxn = 0.f;
        {
            int sn  = (step + 1 < T_SEQ) ? step + 1 : step;
            int ttn = dir ? (T_SEQ - 1 - sn) : sn;
            size_t basen = ((size_t)b * T_SEQ + ttn) * 960 + (size_t)dir * G3;
            if (tid < H) {
                nxr = xw[basen + tid];
                nxz = xw[basen + H + tid];
                nxn = xw[basen + 2 * H + tid];
            }
        }
        // 80-MAC dot, 4 ILP accumulators; LDS reads are 2-address broadcast
        float acc0 = 0.f, acc1 = 0.f, acc2 = 0.f, acc3 = 0.f;
        {
            const float4* hp4 = reinterpret_cast<const float4*>(h_s) + half * 20;
            acc0 += DOT4(hp4[0],  w0);   acc1 += DOT4(hp4[1],  w1);
            acc2 += DOT4(hp4[2],  w2);   acc3 += DOT4(hp4[3],  w3);
            acc0 += DOT4(hp4[4],  w4);   acc1 += DOT4(hp4[5],  w5);
            acc2 += DOT4(hp4[6],  w6);   acc3 += DOT4(hp4[7],  w7);
            acc0 += DOT4(hp4[8],  w8);   acc1 += DOT4(hp4[9],  w9);
            acc2 += DOT4(hp4[10], w10);  acc3 += DOT4(hp4[11], w11);
            acc0 += DOT4(hp4[12], w12);  acc1 += DOT4(hp4[13], w13);
            acc2 += DOT4(hp4[14], w14);  acc3 += DOT4(hp4[15], w15);
            acc0 += DOT4(hp4[16], w16);  acc1 += DOT4(hp4[17], w17);
            acc2 += DOT4(hp4[18], w18);  acc3 += DOT4(hp4[19], w19);
        }
        float s = (acc0 + acc1) + (acc2 + acc3);
        s += __shfl_xor(s, 1);           // partner lane tid^1: full 160-dot
        if (active && half == 0) g_s[r] = s + bias;
        __syncthreads();
        if (tid < H) {
            float rg = sigmoidf_(xr + g_s[tid]);
            float z  = sigmoidf_(xz + g_s[H + tid]);
            float n  = tanhf_(xn + rg * g_s[2 * H + tid]);
            float hn = (1.0f - z) * n + z * h_s[tid];
            h_s[tid] = hn;
            out[((size_t)b * T_SEQ + tt) * 320 + (size_t)dir * H + tid] = hn;
        }
        __syncthreads();
        xr = nxr; xz = nxz; xn = nxn;
    }
}

// ---------------- attn logits: [32768][4] = keys[tok][160] . score_w[h][160] + b ---
__global__ __launch_bounds__(256) void logits_kernel(
    const float* __restrict__ keys, const float* __restrict__ sw,
    const float* __restrict__ sb, float* __restrict__ out)
{
    int gid = blockIdx.x * 256 + threadIdx.x;
    int tok = gid >> 2, h = gid & 3;
    const float4* kr = reinterpret_cast<const float4*>(keys + (size_t)tok * H);
    const float4* wr = reinterpret_cast<const float4*>(sw + (size_t)h * H);
    float acc = 0.f;
    #pragma unroll
    for (int i = 0; i < H / 4; ++i) {
        float4 a = kr[i], w4 = wr[i];
        acc += a.x * w4.x + a.y * w4.y + a.z * w4.z + a.w * w4.w;
    }
    out[gid] = acc + sb[h];
}

// ---------------- epilogue: motion + softmax + pool + proj + LN + L2, 1 block/batch --
__global__ __launch_bounds__(512) void final_kernel(
    const float* __restrict__ x, const float* __restrict__ logits,
    const float* __restrict__ seq, const float* __restrict__ proj_w,
    const float* __restrict__ proj_b, const float* __restrict__ ln_g,
    const float* __restrict__ ln_b, float* __restrict__ out)
{
    int b   = blockIdx.x;
    int tid = threadIdx.x;
    __shared__ float ms[T_SEQ];
    __shared__ float ss[T_SEQ];
    __shared__ __align__(16) float pooled[320];
    __shared__ float red[8];

    // Phase A: motion[t] = ||x[t]-x[t-1]||, m[0]=m[1]; standardize (ddof=1)
    {
        float m = 0.f;
        if (tid >= 1) {
            const float4* xc = reinterpret_cast<const float4*>(x + ((size_t)b * T_SEQ + tid) * DIN);
            const float4* xp = reinterpret_cast<const float4*>(x + ((size_t)b * T_SEQ + tid - 1) * DIN);
            float s = 0.f;
            #pragma unroll
            for (int i = 0; i < DIN / 4; ++i) {
                float4 a = xc[i], p = xp[i];
                float dx = a.x - p.x, dy = a.y - p.y, dz = a.z - p.z, dw = a.w - p.w;
                s += dx * dx + dy * dy + dz * dz + dw * dw;
            }
            m = sqrtf(s);
        }
        ms[tid] = m;
    }
    __syncthreads();
    if (tid == 0) ms[0] = ms[1];
    __syncthreads();
    float mv   = ms[tid];
    float mean = blockReduceSum(mv, red) * (1.0f / T_SEQ);
    float var  = blockReduceSum((mv - mean) * (mv - mean), red) * (1.0f / (T_SEQ - 1));
    float mstd = (mv - mean) / (sqrtf(var) + 1e-6f);

    // Phase B: 4 softmaxes over t; s[t] = mean_h weights
    float4 lg = *reinterpret_cast<const float4*>(logits + ((size_t)b * T_SEQ + tid) * 4);
    float l[4] = {lg.x + mstd, lg.y + mstd, lg.z + mstd, lg.w + mstd};
    float ssum = 0.f;
    #pragma unroll
    for (int h = 0; h < 4; ++h) {
        float mx = blockReduceMax(l[h], red);
        float e  = __expf(l[h] - mx);
        float se = blockReduceSum(e, red);
        float wv = e / se;
        ssum += wv;
    }
    float sv = ssum * 0.25f;
    ss[tid] = sv;
    out[16384 + b * T_SEQ + tid] = sv;   // output 1: weights.mean(axis=2)
    __syncthreads();

    // Phase C: pooled[d] = sum_t seq[b,t,d] * s[t]
    if (tid < 320) {
        float acc = 0.f;
        const float* sp = seq + (size_t)b * T_SEQ * 320 + tid;
        #pragma unroll 4
        for (int t = 0; t < T_SEQ; ++t) acc += sp[(size_t)t * 320] * ss[t];
        pooled[tid] = acc;
    }
    __syncthreads();

    // Phase D: embedding = pooled . proj_w^T + b ; LN ; L2-normalize
    float e = 0.f;
    if (tid < 256) {
        const float4* pw = reinterpret_cast<const float4*>(proj_w + (size_t)tid * 320);
        const float4* pl = reinterpret_cast<const float4*>(pooled);
        float acc = 0.f;
        #pragma unroll
        for (int i = 0; i < 80; ++i) {
            float4 w4 = pw[i], p4 = pl[i];
            acc += w4.x * p4.x + w4.y * p4.y + w4.z * p4.z + w4.w * p4.w;
        }
        e = acc + proj_b[tid];
    }
    float mu = blockReduceSum(tid < 256 ? e : 0.f, red) * (1.0f / 256);
    float dv = (tid < 256) ? (e - mu) : 0.f;
    float vr = blockReduceSum(dv * dv, red) * (1.0f / 256);
    float g  = 0.f;
    if (tid < 256) g = (e - mu) * rsqrtf(vr + 1e-5f) * ln_g[tid] + ln_b[tid];
    float nrm = sqrtf(blockReduceSum(g * g, red));
    nrm = fmaxf(nrm, 1e-12f);
    if (tid < 256) out[b * 256 + tid] = g / nrm;
}

extern "C" void kernel_launch(void* const* d_in, const int* in_sizes, int n_in,
                              void* d_out, int out_size, void* d_ws, size_t ws_size,
                              hipStream_t stream) {
    const float* x       = (const float*)d_in[0];
    const float* Wih0    = (const float*)d_in[1];
    const float* Whh0    = (const float*)d_in[2];
    const float* bih0    = (const float*)d_in[3];
    const float* bhh0    = (const float*)d_in[4];
    const float* Wih1    = (const float*)d_in[5];
    const float* Whh1    = (const float*)d_in[6];
    const float* bih1    = (const float*)d_in[7];
    const float* bhh1    = (const float*)d_in[8];
    const float* key_w   = (const float*)d_in[9];
    const float* key_b   = (const float*)d_in[10];
    const float* score_w = (const float*)d_in[11];
    const float* score_b = (const float*)d_in[12];
    const float* proj_w  = (const float*)d_in[13];
    const float* proj_b  = (const float*)d_in[14];
    const float* ln_g    = (const float*)d_in[15];
    const float* ln_b    = (const float*)d_in[16];

    float* ws    = (float*)d_ws;
    float* xwbuf = ws;                        // 32768*960  = 31457280 (reused for xw1)
    float* h1    = ws + 31457280;             // 32768*320  = 10485760
    float* seq   = h1 + 10485760;             // 32768*320  = 10485760
    float* keys  = seq + 10485760;            // 32768*160  =  5242880
    float* lgts  = keys + 5242880;            // 32768*4    =   131072
    float* outf  = (float*)d_out;

    const int M = BATCH * T_SEQ;              // 32768

    gemm_bias_kernel<<<dim3(M / 64, 15), 256, 0, stream>>>(x,   Wih0, bih0, xwbuf, M, 960, 128, 0);
    gru_kernel<<<128, 1024, 0, stream>>>(xwbuf, Whh0, bhh0, h1);
    gemm_bias_kernel<<<dim3(M / 64, 15), 256, 0, stream>>>(h1,  Wih1, bih1, xwbuf, M, 960, 320, 0);
    gru_kernel<<<128, 1024, 0, stream>>>(xwbuf, Whh1, bhh1, seq);
    gemm_bias_kernel<<<dim3(M / 64, 3),  256, 0, stream>>>(seq, key_w, key_b, keys, M, 160, 320, 1);
    logits_kernel<<<512, 256, 0, stream>>>(keys, score_w, score_b, lgts);
    final_kernel<<<64, 512, 0, stream>>>(x, lgts, seq, proj_w, proj_b, ln_g, ln_b, outf);
}

// Round 6
// 1435.819 us; speedup vs baseline: 1.2575x; 1.2550x over previous
//
#include <hip/hip_runtime.h>
#include <hip/hip_bf16.h>
#include <math.h>

#define T_SEQ 512
#define BATCH 64
#define DIN   128
#define H     160
#define G3    480   // 3*H

typedef _Float16 half8_t __attribute__((ext_vector_type(8)));
typedef _Float16 half2_t __attribute__((ext_vector_type(2)));

__device__ __forceinline__ float sigmoidf_(float x) {
    return 1.0f / (1.0f + __expf(-x));
}
__device__ __forceinline__ float tanhf_(float x) {
    float a = fabsf(x);
    float e = __expf(2.0f * a);
    float t = 1.0f - 2.0f / (e + 1.0f);
    return copysignf(t, x);
}

// 8-element f16 dot, f32 accumulate into 4 independent accumulators.
__device__ __forceinline__ void dot8(const half8_t h, const half8_t w,
                                     float& a0, float& a1, float& a2, float& a3) {
#if __has_builtin(__builtin_amdgcn_fdot2)
    half2_t h01{h[0], h[1]}, h23{h[2], h[3]}, h45{h[4], h[5]}, h67{h[6], h[7]};
    half2_t w01{w[0], w[1]}, w23{w[2], w[3]}, w45{w[4], w[5]}, w67{w[6], w[7]};
    a0 = __builtin_amdgcn_fdot2(h01, w01, a0, false);
    a1 = __builtin_amdgcn_fdot2(h23, w23, a1, false);
    a2 = __builtin_amdgcn_fdot2(h45, w45, a2, false);
    a3 = __builtin_amdgcn_fdot2(h67, w67, a3, false);
#else
    a0 += (float)h[0] * (float)w[0] + (float)h[1] * (float)w[1];
    a1 += (float)h[2] * (float)w[2] + (float)h[3] * (float)w[3];
    a2 += (float)h[4] * (float)w[4] + (float)h[5] * (float)w[5];
    a3 += (float)h[6] * (float)w[6] + (float)h[7] * (float)w[7];
#endif
}

// ---------------- block reductions (512 threads = 8 waves) ----------------
__device__ __forceinline__ float blockReduceSum(float v, float* red) {
    #pragma unroll
    for (int off = 32; off > 0; off >>= 1) v += __shfl_down(v, off, 64);
    int wave = threadIdx.x >> 6, lane = threadIdx.x & 63;
    __syncthreads();                 // protect red from previous use
    if (lane == 0) red[wave] = v;
    __syncthreads();
    float s = red[0];
    int nw = blockDim.x >> 6;
    for (int i = 1; i < nw; ++i) s += red[i];
    return s;
}
__device__ __forceinline__ float blockReduceMax(float v, float* red) {
    #pragma unroll
    for (int off = 32; off > 0; off >>= 1) v = fmaxf(v, __shfl_down(v, off, 64));
    int wave = threadIdx.x >> 6, lane = threadIdx.x & 63;
    __syncthreads();
    if (lane == 0) red[wave] = v;
    __syncthreads();
    float s = red[0];
    int nw = blockDim.x >> 6;
    for (int i = 1; i < nw; ++i) s = fmaxf(s, red[i]);
    return s;
}

// ---------------- f32 -> f16 weight conversion (both layers, one launch) ----
__global__ __launch_bounds__(256) void cvt_weights_kernel(
    const float* __restrict__ w0, const float* __restrict__ w1,
    _Float16* __restrict__ out, int n_per)       // out: [w0 halves][w1 halves]
{
    int i = blockIdx.x * 256 + threadIdx.x;
    if (i < n_per)            out[i] = (_Float16)w0[i];
    else if (i < 2 * n_per)   out[i] = (_Float16)w1[i - n_per];
}

// ---------------- tiled fp32 GEMM: C[M,N] = A[M,K] * B[N,K]^T + bias, opt tanh ----
__global__ __launch_bounds__(256) void gemm_bias_kernel(
    const float* __restrict__ A, const float* __restrict__ B,
    const float* __restrict__ bias, float* __restrict__ C,
    int M, int N, int K, int act)
{
    const int BM = 64, BN = 64, BK = 32;
    __shared__ __align__(16) float As[BK][BM];   // k-major
    __shared__ __align__(16) float Bs[BK][BN];
    int tid  = threadIdx.x;
    int row0 = blockIdx.x * BM;
    int col0 = blockIdx.y * BN;
    int tx = tid & 15, ty = tid >> 4;
    float acc[4][4] = {};

    for (int k0 = 0; k0 < K; k0 += BK) {
        #pragma unroll
        for (int v = 0; v < 2; ++v) {
            int idx = tid + v * 256;       // 0..511 over 64 rows x 8 vec4
            int m   = idx >> 3;
            int kq  = (idx & 7) << 2;
            float4 a4 = *reinterpret_cast<const float4*>(A + (size_t)(row0 + m) * K + k0 + kq);
            As[kq + 0][m] = a4.x; As[kq + 1][m] = a4.y;
            As[kq + 2][m] = a4.z; As[kq + 3][m] = a4.w;
            float4 b4 = make_float4(0.f, 0.f, 0.f, 0.f);
            if (col0 + m < N)
                b4 = *reinterpret_cast<const float4*>(B + (size_t)(col0 + m) * K + k0 + kq);
            Bs[kq + 0][m] = b4.x; Bs[kq + 1][m] = b4.y;
            Bs[kq + 2][m] = b4.z; Bs[kq + 3][m] = b4.w;
        }
        __syncthreads();
        #pragma unroll
        for (int kk = 0; kk < BK; ++kk) {
            float4 a4 = *reinterpret_cast<const float4*>(&As[kk][ty << 2]);
            float4 b4 = *reinterpret_cast<const float4*>(&Bs[kk][tx << 2]);
            float av[4] = {a4.x, a4.y, a4.z, a4.w};
            float bv[4] = {b4.x, b4.y, b4.z, b4.w};
            #pragma unroll
            for (int i = 0; i < 4; ++i)
                #pragma unroll
                for (int j = 0; j < 4; ++j) acc[i][j] += av[i] * bv[j];
        }
        __syncthreads();
    }
    #pragma unroll
    for (int i = 0; i < 4; ++i) {
        int row = row0 + (ty << 2) + i;
        #pragma unroll
        for (int j = 0; j < 4; ++j) {
            int col = col0 + (tx << 2) + j;
            if (col < N) {
                float v = acc[i][j] + bias[col];
                if (act == 1) v = tanhf_(v);
                C[(size_t)row * N + col] = v;
            }
        }
    }
}

// ---------------- GRU recurrence: one block per (batch, dir) ----------------
// 1024 threads; thread = (row r = tid>>1, K-half = tid&1).
// Rounds 1-5 lesson: the allocator refuses to keep 80 fp32 weights live
// (VGPR_Count pinned at 60; it re-streams Whh from L2 every step -> 307
// KB/CU/step -> ~605 us, VALUBusy 35%). Fix: shrink the resident set to fit
// the <=64-VGPR budget -- f16 weights: 80 halves = 10 half8 = 40 VGPRs, and
// the dot uses v_dot2_f32_f16 (f32 accumulate). Hidden state stays fp32 in
// a per-gate-thread register; only the dot operand is f16 (h_h in LDS,
// same-address broadcast reads -> ~free).
// xw: [B][T][960] (dir0: 0..479, dir1: 480..959), whh_h: [2][480][160] f16,
// bhh: [2][480], out: [B][T][320] (dir0 -> 0..159, dir1 -> 160..319)
__global__ __launch_bounds__(1024) void gru_kernel(
    const float* __restrict__ xw, const _Float16* __restrict__ whh_h,
    const float* __restrict__ bhh, float* __restrict__ out)
{
    int b    = blockIdx.x >> 1;
    int dir  = blockIdx.x & 1;
    int tid  = threadIdx.x;
    int r    = tid >> 1;
    int half = tid & 1;
    bool active = (tid < 2 * G3);
    __shared__ __align__(16) _Float16 h_h[H];
    __shared__ float g_s[G3];

    half8_t w0 = {}, w1 = {}, w2 = {}, w3 = {}, w4 = {};
    half8_t w5 = {}, w6 = {}, w7 = {}, w8 = {}, w9 = {};
    float bias = 0.f;
    if (active) {
        const half8_t* wp8 = reinterpret_cast<const half8_t*>(
            whh_h + (size_t)dir * G3 * H + (size_t)r * H + half * 80);
        w0 = wp8[0]; w1 = wp8[1]; w2 = wp8[2]; w3 = wp8[3]; w4 = wp8[4];
        w5 = wp8[5]; w6 = wp8[6]; w7 = wp8[7]; w8 = wp8[8]; w9 = wp8[9];
        bias = bhh[dir * G3 + r];
    }
    if (tid < H) h_h[tid] = (_Float16)0.f;
    float hcur = 0.f;                     // this gate-thread's h element (fp32)
    __syncthreads();

    for (int step = 0; step < T_SEQ; ++step) {
        int tt = dir ? (T_SEQ - 1 - step) : step;
        size_t base = ((size_t)b * T_SEQ + tt) * 960 + (size_t)dir * G3;
        float xr = 0.f, xz = 0.f, xn = 0.f;
        if (tid < H) {   // issue early; latency hides under the dot below
            xr = xw[base + tid];
            xz = xw[base + H + tid];
            xn = xw[base + 2 * H + tid];
        }
        float a0 = 0.f, a1 = 0.f, a2 = 0.f, a3 = 0.f;
        {
            const half8_t* hp8 = reinterpret_cast<const half8_t*>(h_h) + half * 10;
            dot8(hp8[0], w0, a0, a1, a2, a3);
            dot8(hp8[1], w1, a0, a1, a2, a3);
            dot8(hp8[2], w2, a0, a1, a2, a3);
            dot8(hp8[3], w3, a0, a1, a2, a3);
            dot8(hp8[4], w4, a0, a1, a2, a3);
            dot8(hp8[5], w5, a0, a1, a2, a3);
            dot8(hp8[6], w6, a0, a1, a2, a3);
            dot8(hp8[7], w7, a0, a1, a2, a3);
            dot8(hp8[8], w8, a0, a1, a2, a3);
            dot8(hp8[9], w9, a0, a1, a2, a3);
        }
        float s = (a0 + a1) + (a2 + a3);
        s += __shfl_xor(s, 1);           // partner lane tid^1: full 160-dot
        if (active && half == 0) g_s[r] = s + bias;
        __syncthreads();
        if (tid < H) {
            float rg = sigmoidf_(xr + g_s[tid]);
            float z  = sigmoidf_(xz + g_s[H + tid]);
            float n  = tanhf_(xn + rg * g_s[2 * H + tid]);
            float hn = (1.0f - z) * n + z * hcur;
            hcur = hn;
            h_h[tid] = (_Float16)hn;
            out[((size_t)b * T_SEQ + tt) * 320 + (size_t)dir * H + tid] = hn;
        }
        __syncthreads();
    }
}

// ---------------- attn logits: [32768][4] = keys[tok][160] . score_w[h][160] + b ---
__global__ __launch_bounds__(256) void logits_kernel(
    const float* __restrict__ keys, const float* __restrict__ sw,
    const float* __restrict__ sb, float* __restrict__ out)
{
    int gid = blockIdx.x * 256 + threadIdx.x;
    int tok = gid >> 2, h = gid & 3;
    const float4* kr = reinterpret_cast<const float4*>(keys + (size_t)tok * H);
    const float4* wr = reinterpret_cast<const float4*>(sw + (size_t)h * H);
    float acc = 0.f;
    #pragma unroll
    for (int i = 0; i < H / 4; ++i) {
        float4 a = kr[i], w4 = wr[i];
        acc += a.x * w4.x + a.y * w4.y + a.z * w4.z + a.w * w4.w;
    }
    out[gid] = acc + sb[h];
}

// ---------------- epilogue: motion + softmax + pool + proj + LN + L2, 1 block/batch --
__global__ __launch_bounds__(512) void final_kernel(
    const float* __restrict__ x, const float* __restrict__ logits,
    const float* __restrict__ seq, const float* __restrict__ proj_w,
    const float* __restrict__ proj_b, const float* __restrict__ ln_g,
    const float* __restrict__ ln_b, float* __restrict__ out)
{
    int b   = blockIdx.x;
    int tid = threadIdx.x;
    __shared__ float ms[T_SEQ];
    __shared__ float ss[T_SEQ];
    __shared__ __align__(16) float pooled[320];
    __shared__ float red[8];

    // Phase A: motion[t] = ||x[t]-x[t-1]||, m[0]=m[1]; standardize (ddof=1)
    {
        float m = 0.f;
        if (tid >= 1) {
            const float4* xc = reinterpret_cast<const float4*>(x + ((size_t)b * T_SEQ + tid) * DIN);
            const float4* xp = reinterpret_cast<const float4*>(x + ((size_t)b * T_SEQ + tid - 1) * DIN);
            float s = 0.f;
            #pragma unroll
            for (int i = 0; i < DIN / 4; ++i) {
                float4 a = xc[i], p = xp[i];
                float dx = a.x - p.x, dy = a.y - p.y, dz = a.z - p.z, dw = a.w - p.w;
                s += dx * dx + dy * dy + dz * dz + dw * dw;
            }
            m = sqrtf(s);
        }
        ms[tid] = m;
    }
    __syncthreads();
    if (tid == 0) ms[0] = ms[1];
    __syncthreads();
    float mv   = ms[tid];
    float mean = blockReduceSum(mv, red) * (1.0f / T_SEQ);
    float var  = blockReduceSum((mv - mean) * (mv - mean), red) * (1.0f / (T_SEQ - 1));
    float mstd = (mv - mean) / (sqrtf(var) + 1e-6f);

    // Phase B: 4 softmaxes over t; s[t] = mean_h weights
    float4 lg = *reinterpret_cast<const float4*>(logits + ((size_t)b * T_SEQ + tid) * 4);
    float l[4] = {lg.x + mstd, lg.y + mstd, lg.z + mstd, lg.w + mstd};
    float ssum = 0.f;
    #pragma unroll
    for (int h = 0; h < 4; ++h) {
        float mx = blockReduceMax(l[h], red);
        float e  = __expf(l[h] - mx);
        float se = blockReduceSum(e, red);
        float wv = e / se;
        ssum += wv;
    }
    float sv = ssum * 0.25f;
    ss[tid] = sv;
    out[16384 + b * T_SEQ + tid] = sv;   // output 1: weights.mean(axis=2)
    __syncthreads();

    // Phase C: pooled[d] = sum_t seq[b,t,d] * s[t]
    if (tid < 320) {
        float acc = 0.f;
        const float* sp = seq + (size_t)b * T_SEQ * 320 + tid;
        #pragma unroll 4
        for (int t = 0; t < T_SEQ; ++t) acc += sp[(size_t)t * 320] * ss[t];
        pooled[tid] = acc;
    }
    __syncthreads();

    // Phase D: embedding = pooled . proj_w^T + b ; LN ; L2-normalize
    float e = 0.f;
    if (tid < 256) {
        const float4* pw = reinterpret_cast<const float4*>(proj_w + (size_t)tid * 320);
        const float4* pl = reinterpret_cast<const float4*>(pooled);
        float acc = 0.f;
        #pragma unroll
        for (int i = 0; i < 80; ++i) {
            float4 w4 = pw[i], p4 = pl[i];
            acc += w4.x * p4.x + w4.y * p4.y + w4.z * p4.z + w4.w * p4.w;
        }
        e = acc + proj_b[tid];
    }
    float mu = blockReduceSum(tid < 256 ? e : 0.f, red) * (1.0f / 256);
    float dv = (tid < 256) ? (e - mu) : 0.f;
    float vr = blockReduceSum(dv * dv, red) * (1.0f / 256);
    float g  = 0.f;
    if (tid < 256) g = (e - mu) * rsqrtf(vr + 1e-5f) * ln_g[tid] + ln_b[tid];
    float nrm = sqrtf(blockReduceSum(g * g, red));
    nrm = fmaxf(nrm, 1e-12f);
    if (tid < 256) out[b * 256 + tid] = g / nrm;
}

extern "C" void kernel_launch(void* const* d_in, const int* in_sizes, int n_in,
                              void* d_out, int out_size, void* d_ws, size_t ws_size,
                              hipStream_t stream) {
    const float* x       = (const float*)d_in[0];
    const float* Wih0    = (const float*)d_in[1];
    const float* Whh0    = (const float*)d_in[2];
    const float* bih0    = (const float*)d_in[3];
    const float* bhh0    = (const float*)d_in[4];
    const float* Wih1    = (const float*)d_in[5];
    const float* Whh1    = (const float*)d_in[6];
    const float* bih1    = (const float*)d_in[7];
    const float* bhh1    = (const float*)d_in[8];
    const float* key_w   = (const float*)d_in[9];
    const float* key_b   = (const float*)d_in[10];
    const float* score_w = (const float*)d_in[11];
    const float* score_b = (const float*)d_in[12];
    const float* proj_w  = (const float*)d_in[13];
    const float* proj_b  = (const float*)d_in[14];
    const float* ln_g    = (const float*)d_in[15];
    const float* ln_b    = (const float*)d_in[16];

    float* ws    = (float*)d_ws;
    float* xwbuf = ws;                        // 32768*960  = 31457280 (reused for xw1)
    float* h1    = ws + 31457280;             // 32768*320  = 10485760
    float* seq   = h1 + 10485760;             // 32768*320  = 10485760
    float* keys  = seq + 10485760;            // 32768*160  =  5242880
    float* lgts  = keys + 5242880;            // 32768*4    =   131072
    _Float16* whh_h = (_Float16*)(lgts + 131072); // 2 * 153600 halves = 614.4 KB
    float* outf  = (float*)d_out;

    const int M = BATCH * T_SEQ;              // 32768
    const int NW = 2 * G3 * H;                // 153600 elements per layer

    cvt_weights_kernel<<<(2 * NW + 255) / 256, 256, 0, stream>>>(Whh0, Whh1, whh_h, NW);
    gemm_bias_kernel<<<dim3(M / 64, 15), 256, 0, stream>>>(x,   Wih0, bih0, xwbuf, M, 960, 128, 0);
    gru_kernel<<<128, 1024, 0, stream>>>(xwbuf, whh_h,        bhh0, h1);
    gemm_bias_kernel<<<dim3(M / 64, 15), 256, 0, stream>>>(h1,  Wih1, bih1, xwbuf, M, 960, 320, 0);
    gru_kernel<<<128, 1024, 0, stream>>>(xwbuf, whh_h + NW,   bhh1, seq);
    gemm_bias_kernel<<<dim3(M / 64, 3),  256, 0, stream>>>(seq, key_w, key_b, keys, M, 160, 320, 1);
    logits_kernel<<<512, 256, 0, stream>>>(keys, score_w, score_b, lgts);
    final_kernel<<<64, 512, 0, stream>>>(x, lgts, seq, proj_w, proj_b, ln_g, ln_b, outf);
}